// Round 1
// 309.180 us; speedup vs baseline: 1.0212x; 1.0212x over previous
//
#include <hip/hip_runtime.h>
#include <hip/hip_bf16.h>
#include <cstdint>
#include <cstddef>

// Problem: B=4, T=4096, D=1024, H=16, HD=64.
// qkv = x @ Wqkv  (16384x1024 @ 1024x3072)
// per-token head-attention: scores[i,j] = q_i . k_j / 8 over heads i,j (16x16), softmax_j, out = P @ v
// final = out @ Wout (16384x1024 @ 1024x1024)
//
// qkv/ao stored permuted per token (absorbed into weight transposes) so attn
// is fully coalesced. This round: 256^2-tile 8-wave GEMM with 4-slot BK=32
// LDS ring, counted vmcnt(8) (never drained to 0 in the main loop), raw
// s_barrier + explicit lgkmcnt, setprio around the MFMA clusters (T3+T4+T5).

typedef __bf16 bf16x8 __attribute__((ext_vector_type(8)));
typedef __bf16 bf16x4 __attribute__((ext_vector_type(4)));
typedef float  f32x4  __attribute__((ext_vector_type(4)));

#define AS1 __attribute__((address_space(1)))
#define AS3 __attribute__((address_space(3)))

__device__ __forceinline__ void async_copy16(const void* g, void* l) {
    __builtin_amdgcn_global_load_lds((const AS1 void*)g, (AS3 void*)l, 16, 0, 0);
}

// position p in the permuted qkv token-row holds original column pi(p).
// q/k (g<2): col=g*1024+h*64+d -> p = g*1024 + (d&32)*16 + ((d>>3)&3)*128 + h*8 + (d&7)
// v (g==2): col=2048+j*64+d -> p = 2048 + d*16 + j   (V transposed: B-frag direct load)
__device__ __forceinline__ int invp_qkv(int col) {
    int g = col >> 10;
    if (g == 2) { int q = col & 1023; return 2048 + ((q & 63) << 4) + (q >> 6); }
    int h = (col >> 6) & 15, d = col & 63;
    return (g << 10) + ((d & 32) << 4) + (((d >> 3) & 3) << 7) + (h << 3) + (d & 7);
}

// ao position map: original k = i*64+d -> p = (i>>2)*256 + (d&15)*16 + (d>>4)*4 + (i&3)
__device__ __forceinline__ int invp_ao(int k) {
    return (((k >> 8) & 3) << 8) + ((k & 15) << 4) + (((k >> 4) & 3) << 2) + ((k >> 6) & 3);
}

// ---------------- convert fp32 -> bf16 (vectorized) ----------------
__global__ __launch_bounds__(256) void cvt_bf16_kernel(const float4* __restrict__ in,
                                                       bf16x4* __restrict__ out, int n4) {
    int i = blockIdx.x * 256 + threadIdx.x;
    if (i >= n4) return;
    float4 v = in[i];
    bf16x4 o = { (__bf16)v.x, (__bf16)v.y, (__bf16)v.z, (__bf16)v.w };
    out[i] = o;
}

// ---------------- transpose + convert Wqkv: out row order permuted ----------------
__global__ __launch_bounds__(256) void transpose_qkv_kernel(const float* __restrict__ in,
                                                            __bf16* __restrict__ out) {
    __shared__ float tile[32][33];
    const int C = 3072;
    int c0 = blockIdx.x * 32, r0 = blockIdx.y * 32;
    int tx = threadIdx.x, ty = threadIdx.y; // 32 x 8
    #pragma unroll
    for (int i = 0; i < 32; i += 8)
        tile[ty + i][tx] = in[(size_t)(r0 + ty + i) * C + c0 + tx];
    __syncthreads();
    #pragma unroll
    for (int i = 0; i < 32; i += 8) {
        int prow = invp_qkv(c0 + ty + i);
        out[(size_t)prow * 1024 + r0 + tx] = (__bf16)tile[tx][ty + i];
    }
}

// ---------------- transpose + convert Wout: k (inner) order permuted ----------------
__global__ __launch_bounds__(256) void transpose_wout_kernel(const float* __restrict__ in,
                                                             __bf16* __restrict__ out) {
    __shared__ float tile[32][33];
    const int C = 1024;
    int c0 = blockIdx.x * 32, r0 = blockIdx.y * 32;
    int tx = threadIdx.x, ty = threadIdx.y; // 32 x 8
    #pragma unroll
    for (int i = 0; i < 32; i += 8)
        tile[ty + i][tx] = in[(size_t)(r0 + ty + i) * C + c0 + tx];
    __syncthreads();
    int pk = invp_ao(r0 + tx);
    #pragma unroll
    for (int i = 0; i < 32; i += 8)
        out[(size_t)(c0 + ty + i) * 1024 + pk] = (__bf16)tile[tx][ty + i];
}

// ---------------- bf16 GEMM, C = A @ Bt^T, 256x256 tile, BK=32 ring ----------------
// A: M x K bf16 row-major, Bt: N x K bf16 row-major. 512 threads = 8 waves (2Mx4N),
// each wave owns a 128x64 output (acc[8][4] of 16x16 frags).
// LDS: 4-slot ring per matrix, slot = 256 rows x 32 bf16 (64 B row = 4 x 16B phys
// slots, phys = logical_kslot ^ (row&3); staged with pre-swizzled global source so
// global_load_lds dest stays linear). 128 KiB total -> 1 block/CU, 2 waves/SIMD.
// Schedule: 2 phases per K-tile; per phase {ds_read frags | issue 2 gload_lds for
// tile t+3 | s_barrier | lgkmcnt(0) | setprio(1) 16 MFMA setprio(0) | s_barrier}.
// Single counted s_waitcnt vmcnt(8) per K-tile boundary (tiles t+2,t+3 stay in
// flight); never drained to 0 in the main loop.
// Assumes K >= 128 and K % 32 == 0 (here K = 1024).
template<int OUT_BF16>
__global__ __launch_bounds__(512) void gemm_bt(const __bf16* __restrict__ A,
                                               const __bf16* __restrict__ Bt,
                                               void* __restrict__ Cv,
                                               int N, int K) {
    __shared__ __attribute__((aligned(16))) __bf16 As[4 * 256 * 32]; // 64 KB ring
    __shared__ __attribute__((aligned(16))) __bf16 Bs[4 * 256 * 32]; // 64 KB ring

    // XCD-band swizzle (grid % 8 == 0, nby = 64): each XCD owns 8 consecutive
    // A-bands (by), walks bx outer / by inner -> A-bands stay L2-resident.
    const int lin = blockIdx.x;
    const int xcd = lin & 7;
    const int rr  = lin >> 3;
    const int by  = xcd * 8 + (rr & 7);
    const int bx  = rr >> 3;

    const int tid  = threadIdx.x;
    const int wave = tid >> 6;
    const int lane = tid & 63;
    const int quad = lane >> 4;
    const int q16  = lane & 15;
    const int wr   = wave >> 2, wc = wave & 3;  // 2 x 4 wave grid
    const int row0 = by * 256;
    const int col0 = bx * 256;

    const __bf16* Ag = A  + (size_t)row0 * K;
    const __bf16* Bg = Bt + (size_t)col0 * K;

    // staging: thread covers row (g*128 + tid>>2), phys kslot tid&3; source k
    // pre-swizzled so logical slot at phys p is p ^ (row&3).
    const int srow = tid >> 2;                       // 0..127
    const int sk   = ((tid & 3) ^ (srow & 3)) << 3;  // element k-offset 0/8/16/24
    const __bf16* aSrc = Ag + (size_t)srow * K + sk;
    const __bf16* bSrc = Bg + (size_t)srow * K + sk;
    char* aDst = (char*)As + tid * 16;
    char* bDst = (char*)Bs + tid * 16;

    // frag read: phys = quad ^ (row&3); row&3 == q16&3 for every frag row
    const int pxo  = (quad ^ (q16 & 3)) << 4;
    const int aoff = wr * 8192 + q16 * 64 + pxo;   // + p*4096 + mi*1024
    const int boff = wc * 4096 + q16 * 64 + pxo;   // + ni*1024

    f32x4 acc[8][4] = {};

    const int NT = K >> 5;

#define STAGE(t, g) do { \
        const size_t so = (size_t)(g) * 128 * K + (size_t)(t) * 32; \
        const int   dof = ((t) & 3) * 16384 + (g) * 8192; \
        async_copy16(aSrc + so, aDst + dof); \
        async_copy16(bSrc + so, bDst + dof); \
    } while (0)

    // prologue: stage tiles 0..2 (12 loads), wait for tile 0 (8 may remain)
    STAGE(0, 0); STAGE(0, 1);
    STAGE(1, 0); STAGE(1, 1);
    STAGE(2, 0); STAGE(2, 1);
    asm volatile("s_waitcnt vmcnt(8)" ::: "memory");
    __builtin_amdgcn_s_barrier();
    __builtin_amdgcn_sched_barrier(0);

    #pragma unroll 1
    for (int t = 0; t < NT; ++t) {
        const char* Ab = (const char*)As + (t & 3) * 16384;
        const char* Bb = (const char*)Bs + (t & 3) * 16384;
        const bool pf = (t + 3 < NT);

        // ---- phase 0: B frags + A rows 0..3, stage (t+3, g=0) ----
        bf16x8 bf[4], af[4];
        #pragma unroll
        for (int ni = 0; ni < 4; ++ni)
            bf[ni] = *(const bf16x8*)(Bb + boff + ni * 1024);
        #pragma unroll
        for (int mi = 0; mi < 4; ++mi)
            af[mi] = *(const bf16x8*)(Ab + aoff + mi * 1024);
        if (pf) STAGE(t + 3, 0);
        __builtin_amdgcn_sched_barrier(0);
        __builtin_amdgcn_s_barrier();
        asm volatile("s_waitcnt lgkmcnt(0)" ::: "memory");
        __builtin_amdgcn_sched_barrier(0);
        __builtin_amdgcn_s_setprio(1);
        #pragma unroll
        for (int mi = 0; mi < 4; ++mi)
            #pragma unroll
            for (int ni = 0; ni < 4; ++ni)
                acc[mi][ni] = __builtin_amdgcn_mfma_f32_16x16x32_bf16(af[mi], bf[ni], acc[mi][ni], 0, 0, 0);
        __builtin_amdgcn_s_setprio(0);
        __builtin_amdgcn_sched_barrier(0);
        __builtin_amdgcn_s_barrier();

        // ---- phase 1: A rows 4..7, stage (t+3, g=1), counted vmcnt ----
        bf16x8 a2[4];
        #pragma unroll
        for (int mi = 0; mi < 4; ++mi)
            a2[mi] = *(const bf16x8*)(Ab + 4096 + aoff + mi * 1024);
        if (pf) STAGE(t + 3, 1);
        __builtin_amdgcn_sched_barrier(0);
        __builtin_amdgcn_s_barrier();
        asm volatile("s_waitcnt lgkmcnt(0)" ::: "memory");
        __builtin_amdgcn_sched_barrier(0);
        __builtin_amdgcn_s_setprio(1);
        #pragma unroll
        for (int mi = 0; mi < 4; ++mi)
            #pragma unroll
            for (int ni = 0; ni < 4; ++ni)
                acc[mi + 4][ni] = __builtin_amdgcn_mfma_f32_16x16x32_bf16(a2[mi], bf[ni], acc[mi + 4][ni], 0, 0, 0);
        __builtin_amdgcn_s_setprio(0);
        __builtin_amdgcn_sched_barrier(0);
        // tile t+1 must be landed before next phase 0 reads it; allow the
        // 8 loads of tiles t+2 / t+3 to stay in flight (never drain to 0).
        asm volatile("s_waitcnt vmcnt(8)" ::: "memory");
        __builtin_amdgcn_s_barrier();
        __builtin_amdgcn_sched_barrier(0);
    }
#undef STAGE

    // epilogue: D row = quad*4 + r, col = q16 (per 16x16 tile)
    #pragma unroll
    for (int mi = 0; mi < 8; ++mi) {
        #pragma unroll
        for (int ni = 0; ni < 4; ++ni) {
            const int col = col0 + wc * 64 + ni * 16 + q16;
            #pragma unroll
            for (int r = 0; r < 4; ++r) {
                const int row = row0 + wr * 128 + mi * 16 + quad * 4 + r;
                if (OUT_BF16)
                    ((__bf16*)Cv)[(size_t)row * N + col] = (__bf16)acc[mi][ni][r];
                else
                    ((float*)Cv)[(size_t)row * N + col] = acc[mi][ni][r];
            }
        }
    }
}

// ---------------- per-token head attention, MFMA, one wave per token ----------------
// qkv token-row is in permuted layout (see invp_qkv): all loads coalesced,
// V pre-transposed -> direct B-frag loads. No LDS, no barriers.
__global__ __launch_bounds__(256) void attn_mfma_kernel(const __bf16* __restrict__ qkv,
                                                        __bf16* __restrict__ ao) {
    const int tok  = blockIdx.x * 4 + (threadIdx.x >> 6);
    const int lane = threadIdx.x & 63;
    const int quad = lane >> 4;
    const int q16  = lane & 15;

    const __bf16* base = qkv + (size_t)tok * 3072;

    // coalesced A-frag loads (layout puts lane's fragment at lane*8)
    const bf16x8 qf0 = *(const bf16x8*)(base + lane * 8);
    const bf16x8 qf1 = *(const bf16x8*)(base + 512 + lane * 8);
    const bf16x8 kf0 = *(const bf16x8*)(base + 1024 + lane * 8);
    const bf16x8 kf1 = *(const bf16x8*)(base + 1536 + lane * 8);

    // S^T[j][i] = sum_d k[j][d] q[i][d]
    f32x4 st = {0.f, 0.f, 0.f, 0.f};
    st = __builtin_amdgcn_mfma_f32_16x16x32_bf16(kf0, qf0, st, 0, 0, 0);
    st = __builtin_amdgcn_mfma_f32_16x16x32_bf16(kf1, qf1, st, 0, 0, 0);

    // softmax over j (= 4 regs x 4 quads) for fixed i = q16
    float s0 = st[0] * 0.125f, s1 = st[1] * 0.125f, s2 = st[2] * 0.125f, s3 = st[3] * 0.125f;
    float m = fmaxf(fmaxf(s0, s1), fmaxf(s2, s3));
    m = fmaxf(m, __shfl_xor(m, 16));
    m = fmaxf(m, __shfl_xor(m, 32));
    float e0 = __expf(s0 - m), e1 = __expf(s1 - m), e2 = __expf(s2 - m), e3 = __expf(s3 - m);
    float sum = e0 + e1 + e2 + e3;
    sum += __shfl_xor(sum, 16);
    sum += __shfl_xor(sum, 32);
    const float inv = 1.f / sum;

    // pack P^T lane values (j = quad*4 + r, i = q16) into 2 dwords of bf16
    union { __bf16 h[2]; int i; } u01, u23;
    u01.h[0] = (__bf16)(e0 * inv); u01.h[1] = (__bf16)(e1 * inv);
    u23.h[0] = (__bf16)(e2 * inv); u23.h[1] = (__bf16)(e3 * inv);

    // A-frag of P for 16x16x32 (K padded to 32): lane needs P[q16][quad*8+idx]
    const int src0 = quad * 32 + q16;
    const int src1 = src0 + 16;
    union { int i[4]; bf16x8 v; } af;
    af.i[0] = __shfl(u01.i, src0);
    af.i[1] = __shfl(u23.i, src0);
    af.i[2] = __shfl(u01.i, src1);
    af.i[3] = __shfl(u23.i, src1);
    if (quad >= 2) { af.i[0] = 0; af.i[1] = 0; af.i[2] = 0; af.i[3] = 0; }

    // PV: V region is pre-transposed [d][j]; B-frag chunk c is a direct load.
    const __bf16* vb = base + 2048;
    f32x4 accs[4];
    #pragma unroll
    for (int c = 0; c < 4; ++c) {
        bf16x8 bfv = {};
        if (quad < 2)
            bfv = *(const bf16x8*)(vb + (c * 16 + q16) * 16 + quad * 8);
        f32x4 z = {0.f, 0.f, 0.f, 0.f};
        accs[c] = __builtin_amdgcn_mfma_f32_16x16x32_bf16(af.v, bfv, z, 0, 0, 0);
    }

    // store: lane's 16 values contiguously at p = lane*16 (invp_ao layout)
    union { __bf16 h[16]; bf16x8 v[2]; } o;
    #pragma unroll
    for (int c = 0; c < 4; ++c)
        #pragma unroll
        for (int r = 0; r < 4; ++r)
            o.h[c * 4 + r] = (__bf16)accs[c][r];
    __bf16* outp = ao + (size_t)tok * 1024 + lane * 16;
    *(bf16x8*)outp = o.v[0];
    *(bf16x8*)(outp + 8) = o.v[1];
}

// ---------------- launch ----------------
extern "C" void kernel_launch(void* const* d_in, const int* in_sizes, int n_in,
                              void* d_out, int out_size, void* d_ws, size_t ws_size,
                              hipStream_t stream) {
    const float* x    = (const float*)d_in[0]; // 16384 x 1024
    const float* Wqkv = (const float*)d_in[1]; // 1024 x 3072
    const float* Wout = (const float*)d_in[2]; // 1024 x 1024
    float* out = (float*)d_out;                // 16384 x 1024

    char* ws = (char*)d_ws;
    __bf16* xb    = (__bf16*)(ws);                                   // 32 MiB
    __bf16* wqkvT = (__bf16*)(ws + 33554432);                        // 6 MiB  (3072 x 1024, row-permuted)
    __bf16* woutT = (__bf16*)(ws + 33554432 + 6291456);              // 2 MiB  (1024 x 1024, k-permuted)
    __bf16* qkv   = (__bf16*)(ws + 33554432 + 6291456 + 2097152);    // 96 MiB (16384 x 3072, permuted)
    __bf16* ao    = (__bf16*)(ws + 33554432 + 6291456 + 2097152 + 100663296); // 32 MiB (permuted)

    // convert x (16M elems, 4/thread)
    cvt_bf16_kernel<<<16384, 256, 0, stream>>>((const float4*)x, (bf16x4*)xb, 4194304);
    // transpose+convert weights (with absorbed layout permutations)
    transpose_qkv_kernel<<<dim3(96, 32), dim3(32, 8), 0, stream>>>(Wqkv, wqkvT);
    transpose_wout_kernel<<<dim3(32, 32), dim3(32, 8), 0, stream>>>(Wout, woutT);
    // GEMM1: qkv = xb @ wqkvT^T (16384 x 3072), 256^2 tiles: 64 x 12 = 768 blocks
    gemm_bt<1><<<768, 512, 0, stream>>>(xb, wqkvT, (void*)qkv, 3072, 1024);
    // per-token attention (one wave per token, 4 waves/block, no LDS/barrier)
    attn_mfma_kernel<<<4096, 256, 0, stream>>>(qkv, ao);
    // GEMM2: out = ao @ woutT^T (fp32 out), 256^2 tiles: 64 x 4 = 256 blocks
    gemm_bt<0><<<256, 512, 0, stream>>>(ao, woutT, (void*)out, 1024, 1024);
}

// Round 2
// 308.498 us; speedup vs baseline: 1.0235x; 1.0022x over previous
//
#include <hip/hip_runtime.h>
#include <hip/hip_bf16.h>
#include <cstdint>
#include <cstddef>

// Problem: B=4, T=4096, D=1024, H=16, HD=64.
// qkv = x @ Wqkv  (16384x1024 @ 1024x3072)
// per-token head-attention: scores[i,j] = q_i . k_j / 8 over heads i,j (16x16), softmax_j, out = P @ v
// final = out @ Wout (16384x1024 @ 1024x1024)
//
// qkv/ao stored permuted per token (absorbed into weight transposes) so attn
// is fully coalesced. 256^2-tile 8-wave GEMM with 4-slot BK=32 LDS ring,
// counted vmcnt (never drained to 0 mid-loop), raw s_barrier + explicit
// lgkmcnt, setprio around MFMA clusters (T3+T4+T5).
// This round: fix the BK=32 bank swizzle — 64 B rows repeat banks every 2
// rows, so the involution must be phys = slot ^ ((row>>1)&3), not (row&3)
// (round-1 had 9.4M bank conflicts = 4-way on every frag read). Also make
// the end-of-tile vmcnt tail-aware (round-1 raced on the last 3 K-tiles).

typedef __bf16 bf16x8 __attribute__((ext_vector_type(8)));
typedef __bf16 bf16x4 __attribute__((ext_vector_type(4)));
typedef float  f32x4  __attribute__((ext_vector_type(4)));

#define AS1 __attribute__((address_space(1)))
#define AS3 __attribute__((address_space(3)))

__device__ __forceinline__ void async_copy16(const void* g, void* l) {
    __builtin_amdgcn_global_load_lds((const AS1 void*)g, (AS3 void*)l, 16, 0, 0);
}

// position p in the permuted qkv token-row holds original column pi(p).
// q/k (g<2): col=g*1024+h*64+d -> p = g*1024 + (d&32)*16 + ((d>>3)&3)*128 + h*8 + (d&7)
// v (g==2): col=2048+j*64+d -> p = 2048 + d*16 + j   (V transposed: B-frag direct load)
__device__ __forceinline__ int invp_qkv(int col) {
    int g = col >> 10;
    if (g == 2) { int q = col & 1023; return 2048 + ((q & 63) << 4) + (q >> 6); }
    int h = (col >> 6) & 15, d = col & 63;
    return (g << 10) + ((d & 32) << 4) + (((d >> 3) & 3) << 7) + (h << 3) + (d & 7);
}

// ao position map: original k = i*64+d -> p = (i>>2)*256 + (d&15)*16 + (d>>4)*4 + (i&3)
__device__ __forceinline__ int invp_ao(int k) {
    return (((k >> 8) & 3) << 8) + ((k & 15) << 4) + (((k >> 4) & 3) << 2) + ((k >> 6) & 3);
}

// ---------------- convert fp32 -> bf16 (vectorized) ----------------
__global__ __launch_bounds__(256) void cvt_bf16_kernel(const float4* __restrict__ in,
                                                       bf16x4* __restrict__ out, int n4) {
    int i = blockIdx.x * 256 + threadIdx.x;
    if (i >= n4) return;
    float4 v = in[i];
    bf16x4 o = { (__bf16)v.x, (__bf16)v.y, (__bf16)v.z, (__bf16)v.w };
    out[i] = o;
}

// ---------------- transpose + convert Wqkv: out row order permuted ----------------
__global__ __launch_bounds__(256) void transpose_qkv_kernel(const float* __restrict__ in,
                                                            __bf16* __restrict__ out) {
    __shared__ float tile[32][33];
    const int C = 3072;
    int c0 = blockIdx.x * 32, r0 = blockIdx.y * 32;
    int tx = threadIdx.x, ty = threadIdx.y; // 32 x 8
    #pragma unroll
    for (int i = 0; i < 32; i += 8)
        tile[ty + i][tx] = in[(size_t)(r0 + ty + i) * C + c0 + tx];
    __syncthreads();
    #pragma unroll
    for (int i = 0; i < 32; i += 8) {
        int prow = invp_qkv(c0 + ty + i);
        out[(size_t)prow * 1024 + r0 + tx] = (__bf16)tile[tx][ty + i];
    }
}

// ---------------- transpose + convert Wout: k (inner) order permuted ----------------
__global__ __launch_bounds__(256) void transpose_wout_kernel(const float* __restrict__ in,
                                                             __bf16* __restrict__ out) {
    __shared__ float tile[32][33];
    const int C = 1024;
    int c0 = blockIdx.x * 32, r0 = blockIdx.y * 32;
    int tx = threadIdx.x, ty = threadIdx.y; // 32 x 8
    #pragma unroll
    for (int i = 0; i < 32; i += 8)
        tile[ty + i][tx] = in[(size_t)(r0 + ty + i) * C + c0 + tx];
    __syncthreads();
    int pk = invp_ao(r0 + tx);
    #pragma unroll
    for (int i = 0; i < 32; i += 8)
        out[(size_t)(c0 + ty + i) * 1024 + pk] = (__bf16)tile[tx][ty + i];
}

// ---------------- bf16 GEMM, C = A @ Bt^T, 256x256 tile, BK=32 ring ----------------
// A: M x K bf16 row-major, Bt: N x K bf16 row-major. 512 threads = 8 waves (2Mx4N),
// each wave owns a 128x64 output (acc[8][4] of 16x16 frags).
// LDS: 4-slot ring per matrix, slot = 256 rows x 32 bf16. A 64 B row is 4 x 16B
// phys slots; banks repeat every 2 rows (64 B = half the 32-bank width), so the
// conflict-free involution is phys = logical ^ ((row>>1)&3): same-parity frag
// rows spread 2-per-slot -> exactly 8 words/bank per ds_read_b128 (minimum).
// Staged with pre-swizzled global source so global_load_lds dest stays linear.
// 128 KiB total -> 1 block/CU, 2 waves/SIMD.
// Schedule: 2 phases per K-tile; per phase {ds_read frags | issue gload_lds for
// tile t+3 | s_barrier | lgkmcnt(0) | setprio(1) 16 MFMA setprio(0) | s_barrier}.
// End-of-tile counted vmcnt: in-flight = 4*[t+2<NT] + 4*[t+3<NT], so vmcnt(8)
// in steady state (tiles t+2,t+3 in flight), 4 at t==NT-3, 0 after.
// Assumes K >= 128 and K % 32 == 0 (here K = 1024).
template<int OUT_BF16>
__global__ __launch_bounds__(512) void gemm_bt(const __bf16* __restrict__ A,
                                               const __bf16* __restrict__ Bt,
                                               void* __restrict__ Cv,
                                               int N, int K) {
    __shared__ __attribute__((aligned(16))) __bf16 As[4 * 256 * 32]; // 64 KB ring
    __shared__ __attribute__((aligned(16))) __bf16 Bs[4 * 256 * 32]; // 64 KB ring

    // XCD-band swizzle (grid % 8 == 0, nby = 64): each XCD owns 8 consecutive
    // A-bands (by), walks bx outer / by inner -> A-bands stay L2-resident.
    const int lin = blockIdx.x;
    const int xcd = lin & 7;
    const int rr  = lin >> 3;
    const int by  = xcd * 8 + (rr & 7);
    const int bx  = rr >> 3;

    const int tid  = threadIdx.x;
    const int wave = tid >> 6;
    const int lane = tid & 63;
    const int quad = lane >> 4;
    const int q16  = lane & 15;
    const int wr   = wave >> 2, wc = wave & 3;  // 2 x 4 wave grid
    const int row0 = by * 256;
    const int col0 = bx * 256;

    const __bf16* Ag = A  + (size_t)row0 * K;
    const __bf16* Bg = Bt + (size_t)col0 * K;

    // staging: thread covers row (g*128 + tid>>2), phys kslot tid&3; source k
    // pre-swizzled so logical slot at phys p is p ^ ((row>>1)&3).
    const int srow = tid >> 2;                              // 0..127
    const int sk   = ((tid & 3) ^ ((srow >> 1) & 3)) << 3;  // element k-offset 0/8/16/24
    const __bf16* aSrc = Ag + (size_t)srow * K + sk;
    const __bf16* bSrc = Bg + (size_t)srow * K + sk;
    char* aDst = (char*)As + tid * 16;
    char* bDst = (char*)Bs + tid * 16;

    // frag read: phys = quad ^ ((row>>1)&3); (row>>1)&3 == (q16>>1)&3 for every
    // frag row (all row bases are multiples of 16).
    const int pxo  = (quad ^ ((q16 >> 1) & 3)) << 4;
    const int aoff = wr * 8192 + q16 * 64 + pxo;   // + phase*4096 + mi*1024
    const int boff = wc * 4096 + q16 * 64 + pxo;   // + ni*1024

    f32x4 acc[8][4] = {};

    const int NT = K >> 5;

#define STAGE(t, g) do { \
        const size_t so = (size_t)(g) * 128 * K + (size_t)(t) * 32; \
        const int   dof = ((t) & 3) * 16384 + (g) * 8192; \
        async_copy16(aSrc + so, aDst + dof); \
        async_copy16(bSrc + so, bDst + dof); \
    } while (0)

    // prologue: stage tiles 0..2 (12 loads/thread), wait for tile 0 (8 remain)
    STAGE(0, 0); STAGE(0, 1);
    STAGE(1, 0); STAGE(1, 1);
    STAGE(2, 0); STAGE(2, 1);
    asm volatile("s_waitcnt vmcnt(8)" ::: "memory");
    __builtin_amdgcn_s_barrier();
    __builtin_amdgcn_sched_barrier(0);

    #pragma unroll 1
    for (int t = 0; t < NT; ++t) {
        const char* Ab = (const char*)As + (t & 3) * 16384;
        const char* Bb = (const char*)Bs + (t & 3) * 16384;
        const bool pf = (t + 3 < NT);

        // ---- phase 0: B frags + A rows 0..3, stage (t+3, g=0) ----
        bf16x8 bf[4], af[4];
        #pragma unroll
        for (int ni = 0; ni < 4; ++ni)
            bf[ni] = *(const bf16x8*)(Bb + boff + ni * 1024);
        #pragma unroll
        for (int mi = 0; mi < 4; ++mi)
            af[mi] = *(const bf16x8*)(Ab + aoff + mi * 1024);
        if (pf) STAGE(t + 3, 0);
        __builtin_amdgcn_sched_barrier(0);
        __builtin_amdgcn_s_barrier();
        asm volatile("s_waitcnt lgkmcnt(0)" ::: "memory");
        __builtin_amdgcn_sched_barrier(0);
        __builtin_amdgcn_s_setprio(1);
        #pragma unroll
        for (int mi = 0; mi < 4; ++mi)
            #pragma unroll
            for (int ni = 0; ni < 4; ++ni)
                acc[mi][ni] = __builtin_amdgcn_mfma_f32_16x16x32_bf16(af[mi], bf[ni], acc[mi][ni], 0, 0, 0);
        __builtin_amdgcn_s_setprio(0);
        __builtin_amdgcn_sched_barrier(0);
        __builtin_amdgcn_s_barrier();

        // ---- phase 1: A rows 4..7, stage (t+3, g=1), counted vmcnt ----
        bf16x8 a2[4];
        #pragma unroll
        for (int mi = 0; mi < 4; ++mi)
            a2[mi] = *(const bf16x8*)(Ab + 4096 + aoff + mi * 1024);
        if (pf) STAGE(t + 3, 1);
        __builtin_amdgcn_sched_barrier(0);
        __builtin_amdgcn_s_barrier();
        asm volatile("s_waitcnt lgkmcnt(0)" ::: "memory");
        __builtin_amdgcn_sched_barrier(0);
        __builtin_amdgcn_s_setprio(1);
        #pragma unroll
        for (int mi = 0; mi < 4; ++mi)
            #pragma unroll
            for (int ni = 0; ni < 4; ++ni)
                acc[mi + 4][ni] = __builtin_amdgcn_mfma_f32_16x16x32_bf16(a2[mi], bf[ni], acc[mi + 4][ni], 0, 0, 0);
        __builtin_amdgcn_s_setprio(0);
        __builtin_amdgcn_sched_barrier(0);
        // tile t+1 must be landed before next phase 0 reads it. In-flight
        // here: 4 loads for t+2 (if staged) + 4 for t+3 (if staged); count
        // down at the tail (round-1 raced on the last 3 tiles with flat 8).
        if (t < NT - 3)       asm volatile("s_waitcnt vmcnt(8)" ::: "memory");
        else if (t == NT - 3) asm volatile("s_waitcnt vmcnt(4)" ::: "memory");
        else                  asm volatile("s_waitcnt vmcnt(0)" ::: "memory");
        __builtin_amdgcn_s_barrier();
        __builtin_amdgcn_sched_barrier(0);
    }
#undef STAGE

    // epilogue: D row = quad*4 + r, col = q16 (per 16x16 tile)
    #pragma unroll
    for (int mi = 0; mi < 8; ++mi) {
        #pragma unroll
        for (int ni = 0; ni < 4; ++ni) {
            const int col = col0 + wc * 64 + ni * 16 + q16;
            #pragma unroll
            for (int r = 0; r < 4; ++r) {
                const int row = row0 + wr * 128 + mi * 16 + quad * 4 + r;
                if (OUT_BF16)
                    ((__bf16*)Cv)[(size_t)row * N + col] = (__bf16)acc[mi][ni][r];
                else
                    ((float*)Cv)[(size_t)row * N + col] = acc[mi][ni][r];
            }
        }
    }
}

// ---------------- per-token head attention, MFMA, one wave per token ----------------
// qkv token-row is in permuted layout (see invp_qkv): all loads coalesced,
// V pre-transposed -> direct B-frag loads. No LDS, no barriers.
__global__ __launch_bounds__(256) void attn_mfma_kernel(const __bf16* __restrict__ qkv,
                                                        __bf16* __restrict__ ao) {
    const int tok  = blockIdx.x * 4 + (threadIdx.x >> 6);
    const int lane = threadIdx.x & 63;
    const int quad = lane >> 4;
    const int q16  = lane & 15;

    const __bf16* base = qkv + (size_t)tok * 3072;

    // coalesced A-frag loads (layout puts lane's fragment at lane*8)
    const bf16x8 qf0 = *(const bf16x8*)(base + lane * 8);
    const bf16x8 qf1 = *(const bf16x8*)(base + 512 + lane * 8);
    const bf16x8 kf0 = *(const bf16x8*)(base + 1024 + lane * 8);
    const bf16x8 kf1 = *(const bf16x8*)(base + 1536 + lane * 8);

    // S^T[j][i] = sum_d k[j][d] q[i][d]
    f32x4 st = {0.f, 0.f, 0.f, 0.f};
    st = __builtin_amdgcn_mfma_f32_16x16x32_bf16(kf0, qf0, st, 0, 0, 0);
    st = __builtin_amdgcn_mfma_f32_16x16x32_bf16(kf1, qf1, st, 0, 0, 0);

    // softmax over j (= 4 regs x 4 quads) for fixed i = q16
    float s0 = st[0] * 0.125f, s1 = st[1] * 0.125f, s2 = st[2] * 0.125f, s3 = st[3] * 0.125f;
    float m = fmaxf(fmaxf(s0, s1), fmaxf(s2, s3));
    m = fmaxf(m, __shfl_xor(m, 16));
    m = fmaxf(m, __shfl_xor(m, 32));
    float e0 = __expf(s0 - m), e1 = __expf(s1 - m), e2 = __expf(s2 - m), e3 = __expf(s3 - m);
    float sum = e0 + e1 + e2 + e3;
    sum += __shfl_xor(sum, 16);
    sum += __shfl_xor(sum, 32);
    const float inv = 1.f / sum;

    // pack P^T lane values (j = quad*4 + r, i = q16) into 2 dwords of bf16
    union { __bf16 h[2]; int i; } u01, u23;
    u01.h[0] = (__bf16)(e0 * inv); u01.h[1] = (__bf16)(e1 * inv);
    u23.h[0] = (__bf16)(e2 * inv); u23.h[1] = (__bf16)(e3 * inv);

    // A-frag of P for 16x16x32 (K padded to 32): lane needs P[q16][quad*8+idx]
    const int src0 = quad * 32 + q16;
    const int src1 = src0 + 16;
    union { int i[4]; bf16x8 v; } af;
    af.i[0] = __shfl(u01.i, src0);
    af.i[1] = __shfl(u23.i, src0);
    af.i[2] = __shfl(u01.i, src1);
    af.i[3] = __shfl(u23.i, src1);
    if (quad >= 2) { af.i[0] = 0; af.i[1] = 0; af.i[2] = 0; af.i[3] = 0; }

    // PV: V region is pre-transposed [d][j]; B-frag chunk c is a direct load.
    const __bf16* vb = base + 2048;
    f32x4 accs[4];
    #pragma unroll
    for (int c = 0; c < 4; ++c) {
        bf16x8 bfv = {};
        if (quad < 2)
            bfv = *(const bf16x8*)(vb + (c * 16 + q16) * 16 + quad * 8);
        f32x4 z = {0.f, 0.f, 0.f, 0.f};
        accs[c] = __builtin_amdgcn_mfma_f32_16x16x32_bf16(af.v, bfv, z, 0, 0, 0);
    }

    // store: lane's 16 values contiguously at p = lane*16 (invp_ao layout)
    union { __bf16 h[16]; bf16x8 v[2]; } o;
    #pragma unroll
    for (int c = 0; c < 4; ++c)
        #pragma unroll
        for (int r = 0; r < 4; ++r)
            o.h[c * 4 + r] = (__bf16)accs[c][r];
    __bf16* outp = ao + (size_t)tok * 1024 + lane * 16;
    *(bf16x8*)outp = o.v[0];
    *(bf16x8*)(outp + 8) = o.v[1];
}

// ---------------- launch ----------------
extern "C" void kernel_launch(void* const* d_in, const int* in_sizes, int n_in,
                              void* d_out, int out_size, void* d_ws, size_t ws_size,
                              hipStream_t stream) {
    const float* x    = (const float*)d_in[0]; // 16384 x 1024
    const float* Wqkv = (const float*)d_in[1]; // 1024 x 3072
    const float* Wout = (const float*)d_in[2]; // 1024 x 1024
    float* out = (float*)d_out;                // 16384 x 1024

    char* ws = (char*)d_ws;
    __bf16* xb    = (__bf16*)(ws);                                   // 32 MiB
    __bf16* wqkvT = (__bf16*)(ws + 33554432);                        // 6 MiB  (3072 x 1024, row-permuted)
    __bf16* woutT = (__bf16*)(ws + 33554432 + 6291456);              // 2 MiB  (1024 x 1024, k-permuted)
    __bf16* qkv   = (__bf16*)(ws + 33554432 + 6291456 + 2097152);    // 96 MiB (16384 x 3072, permuted)
    __bf16* ao    = (__bf16*)(ws + 33554432 + 6291456 + 2097152 + 100663296); // 32 MiB (permuted)

    // convert x (16M elems, 4/thread)
    cvt_bf16_kernel<<<16384, 256, 0, stream>>>((const float4*)x, (bf16x4*)xb, 4194304);
    // transpose+convert weights (with absorbed layout permutations)
    transpose_qkv_kernel<<<dim3(96, 32), dim3(32, 8), 0, stream>>>(Wqkv, wqkvT);
    transpose_wout_kernel<<<dim3(32, 32), dim3(32, 8), 0, stream>>>(Wout, woutT);
    // GEMM1: qkv = xb @ wqkvT^T (16384 x 3072), 256^2 tiles: 64 x 12 = 768 blocks
    gemm_bt<1><<<768, 512, 0, stream>>>(xb, wqkvT, (void*)qkv, 3072, 1024);
    // per-token attention (one wave per token, 4 waves/block, no LDS/barrier)
    attn_mfma_kernel<<<4096, 256, 0, stream>>>(qkv, ao);
    // GEMM2: out = ao @ woutT^T (fp32 out), 256^2 tiles: 64 x 4 = 256 blocks
    gemm_bt<0><<<256, 512, 0, stream>>>(ao, woutT, (void*)out, 1024, 1024);
}

// Round 3
// 302.718 us; speedup vs baseline: 1.0430x; 1.0191x over previous
//
#include <hip/hip_runtime.h>
#include <hip/hip_bf16.h>
#include <cstdint>
#include <cstddef>

// Problem: B=4, T=4096, D=1024, H=16, HD=64.
// qkv = x @ Wqkv  (16384x1024 @ 1024x3072)
// per-token head-attention: scores[i,j] = q_i . k_j / 8 over heads i,j (16x16), softmax_j, out = P @ v
// final = out @ Wout (16384x1024 @ 1024x1024)
//
// qkv/ao stored permuted per token (absorbed into weight transposes) so attn
// is fully coalesced. 256^2-tile 8-wave GEMM, 4-slot BK=32 LDS ring,
// conflict-free ((row>>1)&3) XOR swizzle (round 2), counted vmcnt.
// This round: software-pipeline the LDS->reg fragment loads ONE PHASE AHEAD.
// Round-2's {read -> barrier -> lgkm(0) -> MFMA} serialized the LDS pipe
// (~1150 cyc/K-tile) against the MFMA pipe (~1240 cyc/K-tile) -> 3025
// cyc/K-tile measured, 36% MfmaUtil. New phase: {issue next-phase ds_reads |
// stage | barrier | MFMA on regs loaded last phase | lgkm(0)} -> reads fly
// on the LDS pipe while the MFMA pipe drains; barriers cut 4 -> 2 per K-tile.
// bf/a03 fragment banks ping-pong by tile parity (loop unrolled x2, all
// indices compile-time).

typedef __bf16 bf16x8 __attribute__((ext_vector_type(8)));
typedef __bf16 bf16x4 __attribute__((ext_vector_type(4)));
typedef float  f32x4  __attribute__((ext_vector_type(4)));

#define AS1 __attribute__((address_space(1)))
#define AS3 __attribute__((address_space(3)))

__device__ __forceinline__ void async_copy16(const void* g, void* l) {
    __builtin_amdgcn_global_load_lds((const AS1 void*)g, (AS3 void*)l, 16, 0, 0);
}

// position p in the permuted qkv token-row holds original column pi(p).
// q/k (g<2): col=g*1024+h*64+d -> p = g*1024 + (d&32)*16 + ((d>>3)&3)*128 + h*8 + (d&7)
// v (g==2): col=2048+j*64+d -> p = 2048 + d*16 + j   (V transposed: B-frag direct load)
__device__ __forceinline__ int invp_qkv(int col) {
    int g = col >> 10;
    if (g == 2) { int q = col & 1023; return 2048 + ((q & 63) << 4) + (q >> 6); }
    int h = (col >> 6) & 15, d = col & 63;
    return (g << 10) + ((d & 32) << 4) + (((d >> 3) & 3) << 7) + (h << 3) + (d & 7);
}

// ao position map: original k = i*64+d -> p = (i>>2)*256 + (d&15)*16 + (d>>4)*4 + (i&3)
__device__ __forceinline__ int invp_ao(int k) {
    return (((k >> 8) & 3) << 8) + ((k & 15) << 4) + (((k >> 4) & 3) << 2) + ((k >> 6) & 3);
}

// ---------------- convert fp32 -> bf16 (vectorized) ----------------
__global__ __launch_bounds__(256) void cvt_bf16_kernel(const float4* __restrict__ in,
                                                       bf16x4* __restrict__ out, int n4) {
    int i = blockIdx.x * 256 + threadIdx.x;
    if (i >= n4) return;
    float4 v = in[i];
    bf16x4 o = { (__bf16)v.x, (__bf16)v.y, (__bf16)v.z, (__bf16)v.w };
    out[i] = o;
}

// ---------------- transpose + convert Wqkv: out row order permuted ----------------
__global__ __launch_bounds__(256) void transpose_qkv_kernel(const float* __restrict__ in,
                                                            __bf16* __restrict__ out) {
    __shared__ float tile[32][33];
    const int C = 3072;
    int c0 = blockIdx.x * 32, r0 = blockIdx.y * 32;
    int tx = threadIdx.x, ty = threadIdx.y; // 32 x 8
    #pragma unroll
    for (int i = 0; i < 32; i += 8)
        tile[ty + i][tx] = in[(size_t)(r0 + ty + i) * C + c0 + tx];
    __syncthreads();
    #pragma unroll
    for (int i = 0; i < 32; i += 8) {
        int prow = invp_qkv(c0 + ty + i);
        out[(size_t)prow * 1024 + r0 + tx] = (__bf16)tile[tx][ty + i];
    }
}

// ---------------- transpose + convert Wout: k (inner) order permuted ----------------
__global__ __launch_bounds__(256) void transpose_wout_kernel(const float* __restrict__ in,
                                                             __bf16* __restrict__ out) {
    __shared__ float tile[32][33];
    const int C = 1024;
    int c0 = blockIdx.x * 32, r0 = blockIdx.y * 32;
    int tx = threadIdx.x, ty = threadIdx.y; // 32 x 8
    #pragma unroll
    for (int i = 0; i < 32; i += 8)
        tile[ty + i][tx] = in[(size_t)(r0 + ty + i) * C + c0 + tx];
    __syncthreads();
    int pk = invp_ao(r0 + tx);
    #pragma unroll
    for (int i = 0; i < 32; i += 8)
        out[(size_t)(c0 + ty + i) * 1024 + pk] = (__bf16)tile[tx][ty + i];
}

// ---------------- bf16 GEMM, C = A @ Bt^T, 256x256 tile, BK=32 ring ----------------
// A: M x K bf16 row-major, Bt: N x K bf16 row-major. 512 threads = 8 waves (2Mx4N),
// each wave owns a 128x64 output (acc[8][4] of 16x16 frags).
// LDS: 4-slot ring per matrix, slot = 256 rows x 32 bf16, conflict-free
// involution phys = logical ^ ((row>>1)&3) (64 B rows repeat banks every 2 rows).
// Pipelined 2-phase schedule per K-tile (frag reads one phase ahead):
//   phase A: issue a47(t) reads | STAGE(t+3,0) | vmcnt(cnt) | barrier |
//            MFMA acc[0..3] (a03(t) x bf(t), loaded last phase) | lgkm(0)
//   phase B: issue bf(t+1), a03(t+1) reads | STAGE(t+3,1) | barrier |
//            MFMA acc[4..7] (a47(t) x bf(t)) | lgkm(0)
// vmcnt ledger at phase A of tile t (everything through S(t+1,1) must land,
// since phase B reads tile t+1): allowed in flight = S(t+2,0),S(t+2,1),
// S(t+3,0) -> 6 steady state, 4 at t==NT-3, 0 after. Barrier A globalizes the
// vmcnt; barrier B is the WAR guard for S(t+4,0) overwriting slot t&3.
// Assumes K >= 128 and K % 64 == 0 (here K = 1024, NT = 32).
template<int OUT_BF16>
__global__ __launch_bounds__(512, 2) void gemm_bt(const __bf16* __restrict__ A,
                                                  const __bf16* __restrict__ Bt,
                                                  void* __restrict__ Cv,
                                                  int N, int K) {
    __shared__ __attribute__((aligned(16))) __bf16 As[4 * 256 * 32]; // 64 KB ring
    __shared__ __attribute__((aligned(16))) __bf16 Bs[4 * 256 * 32]; // 64 KB ring

    // XCD-band swizzle (grid % 8 == 0, nby = 64): each XCD owns 8 consecutive
    // A-bands (by), walks bx outer / by inner -> A-bands stay L2-resident.
    const int lin = blockIdx.x;
    const int xcd = lin & 7;
    const int rr  = lin >> 3;
    const int by  = xcd * 8 + (rr & 7);
    const int bx  = rr >> 3;

    const int tid  = threadIdx.x;
    const int wave = tid >> 6;
    const int lane = tid & 63;
    const int quad = lane >> 4;
    const int q16  = lane & 15;
    const int wr   = wave >> 2, wc = wave & 3;  // 2 x 4 wave grid
    const int row0 = by * 256;
    const int col0 = bx * 256;

    const __bf16* Ag = A  + (size_t)row0 * K;
    const __bf16* Bg = Bt + (size_t)col0 * K;

    // staging: thread covers row (g*128 + tid>>2), phys kslot tid&3; source k
    // pre-swizzled so logical slot at phys p is p ^ ((row>>1)&3).
    const int srow = tid >> 2;                              // 0..127
    const int sk   = ((tid & 3) ^ ((srow >> 1) & 3)) << 3;  // element k-offset
    const __bf16* aSrc = Ag + (size_t)srow * K + sk;
    const __bf16* bSrc = Bg + (size_t)srow * K + sk;
    char* aDst = (char*)As + tid * 16;
    char* bDst = (char*)Bs + tid * 16;

    // frag read: phys = quad ^ ((row>>1)&3); (row>>1)&3 == (q16>>1)&3 for every
    // frag row (all row bases are multiples of 16).
    const int pxo  = (quad ^ ((q16 >> 1) & 3)) << 4;
    const int aoff = wr * 8192 + q16 * 64 + pxo;   // + half*4096 + mi*1024
    const int boff = wc * 4096 + q16 * 64 + pxo;   // + ni*1024

    f32x4 acc[8][4] = {};

    const int NT = K >> 5;

#define STAGE(t, g) do { \
        const size_t so_ = (size_t)(g) * 128 * K + (size_t)(t) * 32; \
        const int   dof_ = ((t) & 3) * 16384 + (g) * 8192; \
        async_copy16(aSrc + so_, aDst + dof_); \
        async_copy16(bSrc + so_, bDst + dof_); \
    } while (0)

    // prologue: stage tiles 0..2 (12 loads/thread), wait tile 0 (8 remain),
    // then preload tile-0 fragment bank A.
    STAGE(0, 0); STAGE(0, 1);
    STAGE(1, 0); STAGE(1, 1);
    STAGE(2, 0); STAGE(2, 1);
    asm volatile("s_waitcnt vmcnt(8)" ::: "memory");
    __builtin_amdgcn_s_barrier();
    __builtin_amdgcn_sched_barrier(0);

    bf16x8 bfA[4], bfB[4], a03A[4], a03B[4], a47[4];
    #pragma unroll
    for (int ni = 0; ni < 4; ++ni)
        bfA[ni] = *(const bf16x8*)((const char*)Bs + boff + ni * 1024);
    #pragma unroll
    for (int mi = 0; mi < 4; ++mi)
        a03A[mi] = *(const bf16x8*)((const char*)As + aoff + mi * 1024);
    asm volatile("s_waitcnt lgkmcnt(0)" ::: "memory");
    __builtin_amdgcn_sched_barrier(0);

#define TILE_STEP(T, BFC, A03C, BFN, A03N) do { \
        const int t_ = (T); \
        const char* Ab_ = (const char*)As + (t_ & 3) * 16384; \
        const char* Bb_ = (const char*)Bs + (t_ & 3) * 16384; \
        /* ---- phase A: issue a47 reads, stage, counted vmcnt, MFMA 0..3 ---- */ \
        _Pragma("unroll") \
        for (int mi = 0; mi < 4; ++mi) \
            a47[mi] = *(const bf16x8*)(Ab_ + 4096 + aoff + mi * 1024); \
        if (t_ + 3 < NT) STAGE(t_ + 3, 0); \
        __builtin_amdgcn_sched_barrier(0); \
        if (t_ < NT - 3)       asm volatile("s_waitcnt vmcnt(6)" ::: "memory"); \
        else if (t_ == NT - 3) asm volatile("s_waitcnt vmcnt(4)" ::: "memory"); \
        else                   asm volatile("s_waitcnt vmcnt(0)" ::: "memory"); \
        __builtin_amdgcn_s_barrier(); \
        __builtin_amdgcn_sched_barrier(0); \
        __builtin_amdgcn_s_setprio(1); \
        _Pragma("unroll") \
        for (int mi = 0; mi < 4; ++mi) \
            _Pragma("unroll") \
            for (int ni = 0; ni < 4; ++ni) \
                acc[mi][ni] = __builtin_amdgcn_mfma_f32_16x16x32_bf16(A03C[mi], BFC[ni], acc[mi][ni], 0, 0, 0); \
        __builtin_amdgcn_s_setprio(0); \
        __builtin_amdgcn_sched_barrier(0); \
        asm volatile("s_waitcnt lgkmcnt(0)" ::: "memory"); \
        __builtin_amdgcn_sched_barrier(0); \
        /* ---- phase B: issue next-tile bf/a03 reads, stage, MFMA 4..7 ---- */ \
        if (t_ + 1 < NT) { \
            const char* Ab1_ = (const char*)As + ((t_ + 1) & 3) * 16384; \
            const char* Bb1_ = (const char*)Bs + ((t_ + 1) & 3) * 16384; \
            _Pragma("unroll") \
            for (int ni = 0; ni < 4; ++ni) \
                BFN[ni] = *(const bf16x8*)(Bb1_ + boff + ni * 1024); \
            _Pragma("unroll") \
            for (int mi = 0; mi < 4; ++mi) \
                A03N[mi] = *(const bf16x8*)(Ab1_ + aoff + mi * 1024); \
        } \
        if (t_ + 3 < NT) STAGE(t_ + 3, 1); \
        __builtin_amdgcn_sched_barrier(0); \
        __builtin_amdgcn_s_barrier(); \
        __builtin_amdgcn_sched_barrier(0); \
        __builtin_amdgcn_s_setprio(1); \
        _Pragma("unroll") \
        for (int mi = 0; mi < 4; ++mi) \
            _Pragma("unroll") \
            for (int ni = 0; ni < 4; ++ni) \
                acc[mi + 4][ni] = __builtin_amdgcn_mfma_f32_16x16x32_bf16(a47[mi], BFC[ni], acc[mi + 4][ni], 0, 0, 0); \
        __builtin_amdgcn_s_setprio(0); \
        __builtin_amdgcn_sched_barrier(0); \
        asm volatile("s_waitcnt lgkmcnt(0)" ::: "memory"); \
        __builtin_amdgcn_sched_barrier(0); \
    } while (0)

    #pragma unroll 1
    for (int t = 0; t < NT; t += 2) {
        TILE_STEP(t,     bfA, a03A, bfB, a03B);
        TILE_STEP(t + 1, bfB, a03B, bfA, a03A);
    }
#undef TILE_STEP
#undef STAGE

    // epilogue: D row = quad*4 + r, col = q16 (per 16x16 tile)
    #pragma unroll
    for (int mi = 0; mi < 8; ++mi) {
        #pragma unroll
        for (int ni = 0; ni < 4; ++ni) {
            const int col = col0 + wc * 64 + ni * 16 + q16;
            #pragma unroll
            for (int r = 0; r < 4; ++r) {
                const int row = row0 + wr * 128 + mi * 16 + quad * 4 + r;
                if (OUT_BF16)
                    ((__bf16*)Cv)[(size_t)row * N + col] = (__bf16)acc[mi][ni][r];
                else
                    ((float*)Cv)[(size_t)row * N + col] = acc[mi][ni][r];
            }
        }
    }
}

// ---------------- per-token head attention, MFMA, one wave per token ----------------
// qkv token-row is in permuted layout (see invp_qkv): all loads coalesced,
// V pre-transposed -> direct B-frag loads. No LDS, no barriers.
__global__ __launch_bounds__(256) void attn_mfma_kernel(const __bf16* __restrict__ qkv,
                                                        __bf16* __restrict__ ao) {
    const int tok  = blockIdx.x * 4 + (threadIdx.x >> 6);
    const int lane = threadIdx.x & 63;
    const int quad = lane >> 4;
    const int q16  = lane & 15;

    const __bf16* base = qkv + (size_t)tok * 3072;

    // coalesced A-frag loads (layout puts lane's fragment at lane*8)
    const bf16x8 qf0 = *(const bf16x8*)(base + lane * 8);
    const bf16x8 qf1 = *(const bf16x8*)(base + 512 + lane * 8);
    const bf16x8 kf0 = *(const bf16x8*)(base + 1024 + lane * 8);
    const bf16x8 kf1 = *(const bf16x8*)(base + 1536 + lane * 8);

    // S^T[j][i] = sum_d k[j][d] q[i][d]
    f32x4 st = {0.f, 0.f, 0.f, 0.f};
    st = __builtin_amdgcn_mfma_f32_16x16x32_bf16(kf0, qf0, st, 0, 0, 0);
    st = __builtin_amdgcn_mfma_f32_16x16x32_bf16(kf1, qf1, st, 0, 0, 0);

    // softmax over j (= 4 regs x 4 quads) for fixed i = q16
    float s0 = st[0] * 0.125f, s1 = st[1] * 0.125f, s2 = st[2] * 0.125f, s3 = st[3] * 0.125f;
    float m = fmaxf(fmaxf(s0, s1), fmaxf(s2, s3));
    m = fmaxf(m, __shfl_xor(m, 16));
    m = fmaxf(m, __shfl_xor(m, 32));
    float e0 = __expf(s0 - m), e1 = __expf(s1 - m), e2 = __expf(s2 - m), e3 = __expf(s3 - m);
    float sum = e0 + e1 + e2 + e3;
    sum += __shfl_xor(sum, 16);
    sum += __shfl_xor(sum, 32);
    const float inv = 1.f / sum;

    // pack P^T lane values (j = quad*4 + r, i = q16) into 2 dwords of bf16
    union { __bf16 h[2]; int i; } u01, u23;
    u01.h[0] = (__bf16)(e0 * inv); u01.h[1] = (__bf16)(e1 * inv);
    u23.h[0] = (__bf16)(e2 * inv); u23.h[1] = (__bf16)(e3 * inv);

    // A-frag of P for 16x16x32 (K padded to 32): lane needs P[q16][quad*8+idx]
    const int src0 = quad * 32 + q16;
    const int src1 = src0 + 16;
    union { int i[4]; bf16x8 v; } af;
    af.i[0] = __shfl(u01.i, src0);
    af.i[1] = __shfl(u23.i, src0);
    af.i[2] = __shfl(u01.i, src1);
    af.i[3] = __shfl(u23.i, src1);
    if (quad >= 2) { af.i[0] = 0; af.i[1] = 0; af.i[2] = 0; af.i[3] = 0; }

    // PV: V region is pre-transposed [d][j]; B-frag chunk c is a direct load.
    const __bf16* vb = base + 2048;
    f32x4 accs[4];
    #pragma unroll
    for (int c = 0; c < 4; ++c) {
        bf16x8 bfv = {};
        if (quad < 2)
            bfv = *(const bf16x8*)(vb + (c * 16 + q16) * 16 + quad * 8);
        f32x4 z = {0.f, 0.f, 0.f, 0.f};
        accs[c] = __builtin_amdgcn_mfma_f32_16x16x32_bf16(af.v, bfv, z, 0, 0, 0);
    }

    // store: lane's 16 values contiguously at p = lane*16 (invp_ao layout)
    union { __bf16 h[16]; bf16x8 v[2]; } o;
    #pragma unroll
    for (int c = 0; c < 4; ++c)
        #pragma unroll
        for (int r = 0; r < 4; ++r)
            o.h[c * 4 + r] = (__bf16)accs[c][r];
    __bf16* outp = ao + (size_t)tok * 1024 + lane * 16;
    *(bf16x8*)outp = o.v[0];
    *(bf16x8*)(outp + 8) = o.v[1];
}

// ---------------- launch ----------------
extern "C" void kernel_launch(void* const* d_in, const int* in_sizes, int n_in,
                              void* d_out, int out_size, void* d_ws, size_t ws_size,
                              hipStream_t stream) {
    const float* x    = (const float*)d_in[0]; // 16384 x 1024
    const float* Wqkv = (const float*)d_in[1]; // 1024 x 3072
    const float* Wout = (const float*)d_in[2]; // 1024 x 1024
    float* out = (float*)d_out;                // 16384 x 1024

    char* ws = (char*)d_ws;
    __bf16* xb    = (__bf16*)(ws);                                   // 32 MiB
    __bf16* wqkvT = (__bf16*)(ws + 33554432);                        // 6 MiB  (3072 x 1024, row-permuted)
    __bf16* woutT = (__bf16*)(ws + 33554432 + 6291456);              // 2 MiB  (1024 x 1024, k-permuted)
    __bf16* qkv   = (__bf16*)(ws + 33554432 + 6291456 + 2097152);    // 96 MiB (16384 x 3072, permuted)
    __bf16* ao    = (__bf16*)(ws + 33554432 + 6291456 + 2097152 + 100663296); // 32 MiB (permuted)

    // convert x (16M elems, 4/thread)
    cvt_bf16_kernel<<<16384, 256, 0, stream>>>((const float4*)x, (bf16x4*)xb, 4194304);
    // transpose+convert weights (with absorbed layout permutations)
    transpose_qkv_kernel<<<dim3(96, 32), dim3(32, 8), 0, stream>>>(Wqkv, wqkvT);
    transpose_wout_kernel<<<dim3(32, 32), dim3(32, 8), 0, stream>>>(Wout, woutT);
    // GEMM1: qkv = xb @ wqkvT^T (16384 x 3072), 256^2 tiles: 64 x 12 = 768 blocks
    gemm_bt<1><<<768, 512, 0, stream>>>(xb, wqkvT, (void*)qkv, 3072, 1024);
    // per-token attention (one wave per token, 4 waves/block, no LDS/barrier)
    attn_mfma_kernel<<<4096, 256, 0, stream>>>(qkv, ao);
    // GEMM2: out = ao @ woutT^T (fp32 out), 256^2 tiles: 64 x 4 = 256 blocks
    gemm_bt<0><<<256, 512, 0, stream>>>(ao, woutT, (void*)out, 1024, 1024);
}

// Round 4
// 296.696 us; speedup vs baseline: 1.0642x; 1.0203x over previous
//
#include <hip/hip_runtime.h>
#include <hip/hip_bf16.h>
#include <cstdint>
#include <cstddef>

// Problem: B=4, T=4096, D=1024, H=16, HD=64.
// qkv = x @ Wqkv  (16384x1024 @ 1024x3072)
// per-token head-attention: scores[i,j] = q_i . k_j / 8 over heads i,j (16x16), softmax_j, out = P @ v
// final = out @ Wout (16384x1024 @ 1024x1024)
//
// qkv/ao stored permuted per token (absorbed into weight transposes) so attn
// is fully coalesced. 256^2-tile 8-wave GEMM, 4-slot BK=32 LDS ring,
// conflict-free ((row>>1)&3) XOR swizzle, counted vmcnt.
// This round: MFMA-FIRST phase order. Round-3's {reads|stage|vmcnt|bar|MFMA}
// left the vmcnt stall serialized against an idle MFMA pipe (measured 2866
// cyc/K-tile vs 1242 MFMA floor). New phase: {lgkm|MFMA on last-phase regs|
// reads(next)|STAGE|[vmcnt]|bar} — the staging wait and ds_read latency now
// overlap the MFMA pipe drain. One vmcnt per K-tile (phase A only; ledger
// re-derived), 2 barriers per K-tile.

typedef __bf16 bf16x8 __attribute__((ext_vector_type(8)));
typedef __bf16 bf16x4 __attribute__((ext_vector_type(4)));
typedef float  f32x4  __attribute__((ext_vector_type(4)));

#define AS1 __attribute__((address_space(1)))
#define AS3 __attribute__((address_space(3)))

__device__ __forceinline__ void async_copy16(const void* g, void* l) {
    __builtin_amdgcn_global_load_lds((const AS1 void*)g, (AS3 void*)l, 16, 0, 0);
}

// position p in the permuted qkv token-row holds original column pi(p).
// q/k (g<2): col=g*1024+h*64+d -> p = g*1024 + (d&32)*16 + ((d>>3)&3)*128 + h*8 + (d&7)
// v (g==2): col=2048+j*64+d -> p = 2048 + d*16 + j   (V transposed: B-frag direct load)
__device__ __forceinline__ int invp_qkv(int col) {
    int g = col >> 10;
    if (g == 2) { int q = col & 1023; return 2048 + ((q & 63) << 4) + (q >> 6); }
    int h = (col >> 6) & 15, d = col & 63;
    return (g << 10) + ((d & 32) << 4) + (((d >> 3) & 3) << 7) + (h << 3) + (d & 7);
}

// ao position map: original k = i*64+d -> p = (i>>2)*256 + (d&15)*16 + (d>>4)*4 + (i&3)
__device__ __forceinline__ int invp_ao(int k) {
    return (((k >> 8) & 3) << 8) + ((k & 15) << 4) + (((k >> 4) & 3) << 2) + ((k >> 6) & 3);
}

// ---------------- convert fp32 -> bf16 (vectorized) ----------------
__global__ __launch_bounds__(256) void cvt_bf16_kernel(const float4* __restrict__ in,
                                                       bf16x4* __restrict__ out, int n4) {
    int i = blockIdx.x * 256 + threadIdx.x;
    if (i >= n4) return;
    float4 v = in[i];
    bf16x4 o = { (__bf16)v.x, (__bf16)v.y, (__bf16)v.z, (__bf16)v.w };
    out[i] = o;
}

// ---------------- transpose + convert Wqkv: out row order permuted ----------------
__global__ __launch_bounds__(256) void transpose_qkv_kernel(const float* __restrict__ in,
                                                            __bf16* __restrict__ out) {
    __shared__ float tile[32][33];
    const int C = 3072;
    int c0 = blockIdx.x * 32, r0 = blockIdx.y * 32;
    int tx = threadIdx.x, ty = threadIdx.y; // 32 x 8
    #pragma unroll
    for (int i = 0; i < 32; i += 8)
        tile[ty + i][tx] = in[(size_t)(r0 + ty + i) * C + c0 + tx];
    __syncthreads();
    #pragma unroll
    for (int i = 0; i < 32; i += 8) {
        int prow = invp_qkv(c0 + ty + i);
        out[(size_t)prow * 1024 + r0 + tx] = (__bf16)tile[tx][ty + i];
    }
}

// ---------------- transpose + convert Wout: k (inner) order permuted ----------------
__global__ __launch_bounds__(256) void transpose_wout_kernel(const float* __restrict__ in,
                                                             __bf16* __restrict__ out) {
    __shared__ float tile[32][33];
    const int C = 1024;
    int c0 = blockIdx.x * 32, r0 = blockIdx.y * 32;
    int tx = threadIdx.x, ty = threadIdx.y; // 32 x 8
    #pragma unroll
    for (int i = 0; i < 32; i += 8)
        tile[ty + i][tx] = in[(size_t)(r0 + ty + i) * C + c0 + tx];
    __syncthreads();
    int pk = invp_ao(r0 + tx);
    #pragma unroll
    for (int i = 0; i < 32; i += 8)
        out[(size_t)(c0 + ty + i) * 1024 + pk] = (__bf16)tile[tx][ty + i];
}

// ---------------- bf16 GEMM, C = A @ Bt^T, 256x256 tile, BK=32 ring ----------------
// A: M x K bf16 row-major, Bt: N x K bf16 row-major. 512 threads = 8 waves (2Mx4N),
// each wave owns a 128x64 output (acc[8][4] of 16x16 frags).
// LDS: 4-slot ring per matrix, slot = 256 rows x 32 bf16, conflict-free
// involution phys = logical ^ ((row>>1)&3) (64 B rows repeat banks every 2 rows).
// MFMA-first 2-phase schedule per K-tile t (frag regs loaded one phase ahead):
//   phase A: lgkm(0) | MFMA acc[0..3] (a03(t) x bf(t)) | read a47(t) |
//            STAGE(t+3,0) | vmcnt(cnt) | barrier
//   phase B: lgkm(0) | MFMA acc[4..7] (a47(t) x bf(t)) | read bf(t+1),a03(t+1) |
//            STAGE(t+3,1) | barrier
// vmcnt ledger at phase A of tile t (tile t+1 must be landed before phase B's
// reads): queue after S(t+1,1) = S(t+2,0),S(t+2,1),S(t+3,0) -> 6 steady,
// 4 at t==NT-3, 0 after. Barrier A globalizes the vmcnt; barrier B is the WAR
// guard (all waves' tile-t reads retire at B's lgkm before A(t+1)'s STAGE
// overwrites slot t&3). The vmcnt stall and ds_read latency overlap the MFMA
// pipe drain of the cluster issued just before them.
// Assumes K >= 128 and K % 64 == 0 (here K = 1024, NT = 32).
template<int OUT_BF16>
__global__ __launch_bounds__(512, 2) void gemm_bt(const __bf16* __restrict__ A,
                                                  const __bf16* __restrict__ Bt,
                                                  void* __restrict__ Cv,
                                                  int N, int K) {
    __shared__ __attribute__((aligned(16))) __bf16 As[4 * 256 * 32]; // 64 KB ring
    __shared__ __attribute__((aligned(16))) __bf16 Bs[4 * 256 * 32]; // 64 KB ring

    // XCD-band swizzle (grid % 8 == 0, nby = 64): each XCD owns 8 consecutive
    // A-bands (by), walks bx outer / by inner -> A-bands stay L2-resident.
    const int lin = blockIdx.x;
    const int xcd = lin & 7;
    const int rr  = lin >> 3;
    const int by  = xcd * 8 + (rr & 7);
    const int bx  = rr >> 3;

    const int tid  = threadIdx.x;
    const int wave = tid >> 6;
    const int lane = tid & 63;
    const int quad = lane >> 4;
    const int q16  = lane & 15;
    const int wr   = wave >> 2, wc = wave & 3;  // 2 x 4 wave grid
    const int row0 = by * 256;
    const int col0 = bx * 256;

    const __bf16* Ag = A  + (size_t)row0 * K;
    const __bf16* Bg = Bt + (size_t)col0 * K;

    // staging: thread covers row (g*128 + tid>>2), phys kslot tid&3; source k
    // pre-swizzled so logical slot at phys p is p ^ ((row>>1)&3).
    const int srow = tid >> 2;                              // 0..127
    const int sk   = ((tid & 3) ^ ((srow >> 1) & 3)) << 3;  // element k-offset
    const __bf16* aSrc = Ag + (size_t)srow * K + sk;
    const __bf16* bSrc = Bg + (size_t)srow * K + sk;
    char* aDst = (char*)As + tid * 16;
    char* bDst = (char*)Bs + tid * 16;

    // frag read: phys = quad ^ ((row>>1)&3); (row>>1)&3 == (q16>>1)&3 for every
    // frag row (all row bases are multiples of 16).
    const int pxo  = (quad ^ ((q16 >> 1) & 3)) << 4;
    const int aoff = wr * 8192 + q16 * 64 + pxo;   // + half*4096 + mi*1024
    const int boff = wc * 4096 + q16 * 64 + pxo;   // + ni*1024

    f32x4 acc[8][4] = {};

    const int NT = K >> 5;

#define STAGE(t, g) do { \
        const size_t so_ = (size_t)(g) * 128 * K + (size_t)(t) * 32; \
        const int   dof_ = ((t) & 3) * 16384 + (g) * 8192; \
        async_copy16(aSrc + so_, aDst + dof_); \
        async_copy16(bSrc + so_, bDst + dof_); \
    } while (0)

    // prologue: stage tiles 0..2 (12 loads/thread), wait tile 0 (8 remain),
    // then preload tile-0 fragment bank A (awaited by A(0)'s lgkm).
    STAGE(0, 0); STAGE(0, 1);
    STAGE(1, 0); STAGE(1, 1);
    STAGE(2, 0); STAGE(2, 1);
    asm volatile("s_waitcnt vmcnt(8)" ::: "memory");
    __builtin_amdgcn_s_barrier();
    __builtin_amdgcn_sched_barrier(0);

    bf16x8 bfA[4], bfB[4], a03A[4], a03B[4], a47[4];
    #pragma unroll
    for (int ni = 0; ni < 4; ++ni)
        bfA[ni] = *(const bf16x8*)((const char*)Bs + boff + ni * 1024);
    #pragma unroll
    for (int mi = 0; mi < 4; ++mi)
        a03A[mi] = *(const bf16x8*)((const char*)As + aoff + mi * 1024);
    __builtin_amdgcn_sched_barrier(0);

#define TILE_STEP(T, BFC, A03C, BFN, A03N) do { \
        const int t_ = (T); \
        const char* Ab_ = (const char*)As + (t_ & 3) * 16384; \
        /* ---- phase A: MFMA acc[0..3] on last-phase regs; then a47 reads, ---- */ \
        /* ---- stage, counted vmcnt, barrier                              ---- */ \
        asm volatile("s_waitcnt lgkmcnt(0)" ::: "memory"); \
        __builtin_amdgcn_sched_barrier(0); \
        __builtin_amdgcn_s_setprio(1); \
        _Pragma("unroll") \
        for (int mi = 0; mi < 4; ++mi) \
            _Pragma("unroll") \
            for (int ni = 0; ni < 4; ++ni) \
                acc[mi][ni] = __builtin_amdgcn_mfma_f32_16x16x32_bf16(A03C[mi], BFC[ni], acc[mi][ni], 0, 0, 0); \
        __builtin_amdgcn_s_setprio(0); \
        __builtin_amdgcn_sched_barrier(0); \
        _Pragma("unroll") \
        for (int mi = 0; mi < 4; ++mi) \
            a47[mi] = *(const bf16x8*)(Ab_ + 4096 + aoff + mi * 1024); \
        if (t_ + 3 < NT) STAGE(t_ + 3, 0); \
        __builtin_amdgcn_sched_barrier(0); \
        if (t_ < NT - 3)       asm volatile("s_waitcnt vmcnt(6)" ::: "memory"); \
        else if (t_ == NT - 3) asm volatile("s_waitcnt vmcnt(4)" ::: "memory"); \
        else                   asm volatile("s_waitcnt vmcnt(0)" ::: "memory"); \
        __builtin_amdgcn_s_barrier(); \
        __builtin_amdgcn_sched_barrier(0); \
        /* ---- phase B: MFMA acc[4..7]; then next-tile bf/a03 reads, stage, ---- */ \
        /* ---- barrier (WAR guard for A(t+1)'s STAGE into slot t&3)        ---- */ \
        asm volatile("s_waitcnt lgkmcnt(0)" ::: "memory"); \
        __builtin_amdgcn_sched_barrier(0); \
        __builtin_amdgcn_s_setprio(1); \
        _Pragma("unroll") \
        for (int mi = 0; mi < 4; ++mi) \
            _Pragma("unroll") \
            for (int ni = 0; ni < 4; ++ni) \
                acc[mi + 4][ni] = __builtin_amdgcn_mfma_f32_16x16x32_bf16(a47[mi], BFC[ni], acc[mi + 4][ni], 0, 0, 0); \
        __builtin_amdgcn_s_setprio(0); \
        __builtin_amdgcn_sched_barrier(0); \
        if (t_ + 1 < NT) { \
            const char* Ab1_ = (const char*)As + ((t_ + 1) & 3) * 16384; \
            const char* Bb1_ = (const char*)Bs + ((t_ + 1) & 3) * 16384; \
            _Pragma("unroll") \
            for (int ni = 0; ni < 4; ++ni) \
                BFN[ni] = *(const bf16x8*)(Bb1_ + boff + ni * 1024); \
            _Pragma("unroll") \
            for (int mi = 0; mi < 4; ++mi) \
                A03N[mi] = *(const bf16x8*)(Ab1_ + aoff + mi * 1024); \
        } \
        if (t_ + 3 < NT) STAGE(t_ + 3, 1); \
        __builtin_amdgcn_sched_barrier(0); \
        __builtin_amdgcn_s_barrier(); \
        __builtin_amdgcn_sched_barrier(0); \
    } while (0)

    #pragma unroll 1
    for (int t = 0; t < NT; t += 2) {
        TILE_STEP(t,     bfA, a03A, bfB, a03B);
        TILE_STEP(t + 1, bfB, a03B, bfA, a03A);
    }
#undef TILE_STEP
#undef STAGE

    // epilogue: D row = quad*4 + r, col = q16 (per 16x16 tile)
    #pragma unroll
    for (int mi = 0; mi < 8; ++mi) {
        #pragma unroll
        for (int ni = 0; ni < 4; ++ni) {
            const int col = col0 + wc * 64 + ni * 16 + q16;
            #pragma unroll
            for (int r = 0; r < 4; ++r) {
                const int row = row0 + wr * 128 + mi * 16 + quad * 4 + r;
                if (OUT_BF16)
                    ((__bf16*)Cv)[(size_t)row * N + col] = (__bf16)acc[mi][ni][r];
                else
                    ((float*)Cv)[(size_t)row * N + col] = acc[mi][ni][r];
            }
        }
    }
}

// ---------------- per-token head attention, MFMA, one wave per token ----------------
// qkv token-row is in permuted layout (see invp_qkv): all loads coalesced,
// V pre-transposed -> direct B-frag loads. No LDS, no barriers.
__global__ __launch_bounds__(256) void attn_mfma_kernel(const __bf16* __restrict__ qkv,
                                                        __bf16* __restrict__ ao) {
    const int tok  = blockIdx.x * 4 + (threadIdx.x >> 6);
    const int lane = threadIdx.x & 63;
    const int quad = lane >> 4;
    const int q16  = lane & 15;

    const __bf16* base = qkv + (size_t)tok * 3072;

    // coalesced A-frag loads (layout puts lane's fragment at lane*8)
    const bf16x8 qf0 = *(const bf16x8*)(base + lane * 8);
    const bf16x8 qf1 = *(const bf16x8*)(base + 512 + lane * 8);
    const bf16x8 kf0 = *(const bf16x8*)(base + 1024 + lane * 8);
    const bf16x8 kf1 = *(const bf16x8*)(base + 1536 + lane * 8);

    // S^T[j][i] = sum_d k[j][d] q[i][d]
    f32x4 st = {0.f, 0.f, 0.f, 0.f};
    st = __builtin_amdgcn_mfma_f32_16x16x32_bf16(kf0, qf0, st, 0, 0, 0);
    st = __builtin_amdgcn_mfma_f32_16x16x32_bf16(kf1, qf1, st, 0, 0, 0);

    // softmax over j (= 4 regs x 4 quads) for fixed i = q16
    float s0 = st[0] * 0.125f, s1 = st[1] * 0.125f, s2 = st[2] * 0.125f, s3 = st[3] * 0.125f;
    float m = fmaxf(fmaxf(s0, s1), fmaxf(s2, s3));
    m = fmaxf(m, __shfl_xor(m, 16));
    m = fmaxf(m, __shfl_xor(m, 32));
    float e0 = __expf(s0 - m), e1 = __expf(s1 - m), e2 = __expf(s2 - m), e3 = __expf(s3 - m);
    float sum = e0 + e1 + e2 + e3;
    sum += __shfl_xor(sum, 16);
    sum += __shfl_xor(sum, 32);
    const float inv = 1.f / sum;

    // pack P^T lane values (j = quad*4 + r, i = q16) into 2 dwords of bf16
    union { __bf16 h[2]; int i; } u01, u23;
    u01.h[0] = (__bf16)(e0 * inv); u01.h[1] = (__bf16)(e1 * inv);
    u23.h[0] = (__bf16)(e2 * inv); u23.h[1] = (__bf16)(e3 * inv);

    // A-frag of P for 16x16x32 (K padded to 32): lane needs P[q16][quad*8+idx]
    const int src0 = quad * 32 + q16;
    const int src1 = src0 + 16;
    union { int i[4]; bf16x8 v; } af;
    af.i[0] = __shfl(u01.i, src0);
    af.i[1] = __shfl(u23.i, src0);
    af.i[2] = __shfl(u01.i, src1);
    af.i[3] = __shfl(u23.i, src1);
    if (quad >= 2) { af.i[0] = 0; af.i[1] = 0; af.i[2] = 0; af.i[3] = 0; }

    // PV: V region is pre-transposed [d][j]; B-frag chunk c is a direct load.
    const __bf16* vb = base + 2048;
    f32x4 accs[4];
    #pragma unroll
    for (int c = 0; c < 4; ++c) {
        bf16x8 bfv = {};
        if (quad < 2)
            bfv = *(const bf16x8*)(vb + (c * 16 + q16) * 16 + quad * 8);
        f32x4 z = {0.f, 0.f, 0.f, 0.f};
        accs[c] = __builtin_amdgcn_mfma_f32_16x16x32_bf16(af.v, bfv, z, 0, 0, 0);
    }

    // store: lane's 16 values contiguously at p = lane*16 (invp_ao layout)
    union { __bf16 h[16]; bf16x8 v[2]; } o;
    #pragma unroll
    for (int c = 0; c < 4; ++c)
        #pragma unroll
        for (int r = 0; r < 4; ++r)
            o.h[c * 4 + r] = (__bf16)accs[c][r];
    __bf16* outp = ao + (size_t)tok * 1024 + lane * 16;
    *(bf16x8*)outp = o.v[0];
    *(bf16x8*)(outp + 8) = o.v[1];
}

// ---------------- launch ----------------
extern "C" void kernel_launch(void* const* d_in, const int* in_sizes, int n_in,
                              void* d_out, int out_size, void* d_ws, size_t ws_size,
                              hipStream_t stream) {
    const float* x    = (const float*)d_in[0]; // 16384 x 1024
    const float* Wqkv = (const float*)d_in[1]; // 1024 x 3072
    const float* Wout = (const float*)d_in[2]; // 1024 x 1024
    float* out = (float*)d_out;                // 16384 x 1024

    char* ws = (char*)d_ws;
    __bf16* xb    = (__bf16*)(ws);                                   // 32 MiB
    __bf16* wqkvT = (__bf16*)(ws + 33554432);                        // 6 MiB  (3072 x 1024, row-permuted)
    __bf16* woutT = (__bf16*)(ws + 33554432 + 6291456);              // 2 MiB  (1024 x 1024, k-permuted)
    __bf16* qkv   = (__bf16*)(ws + 33554432 + 6291456 + 2097152);    // 96 MiB (16384 x 3072, permuted)
    __bf16* ao    = (__bf16*)(ws + 33554432 + 6291456 + 2097152 + 100663296); // 32 MiB (permuted)

    // convert x (16M elems, 4/thread)
    cvt_bf16_kernel<<<16384, 256, 0, stream>>>((const float4*)x, (bf16x4*)xb, 4194304);
    // transpose+convert weights (with absorbed layout permutations)
    transpose_qkv_kernel<<<dim3(96, 32), dim3(32, 8), 0, stream>>>(Wqkv, wqkvT);
    transpose_wout_kernel<<<dim3(32, 32), dim3(32, 8), 0, stream>>>(Wout, woutT);
    // GEMM1: qkv = xb @ wqkvT^T (16384 x 3072), 256^2 tiles: 64 x 12 = 768 blocks
    gemm_bt<1><<<768, 512, 0, stream>>>(xb, wqkvT, (void*)qkv, 3072, 1024);
    // per-token attention (one wave per token, 4 waves/block, no LDS/barrier)
    attn_mfma_kernel<<<4096, 256, 0, stream>>>(qkv, ao);
    // GEMM2: out = ao @ woutT^T (fp32 out), 256^2 tiles: 64 x 4 = 256 blocks
    gemm_bt<0><<<256, 512, 0, stream>>>(ao, woutT, (void*)out, 1024, 1024);
}